// Round 10
// baseline (5751.544 us; speedup 1.0000x reference)
//
#include <hip/hip_runtime.h>
#include <hip/hip_bf16.h>
#include <stdint.h>

// Problem dims
#define BB 64     // batch
#define SS 512    // seq len
#define HH 512    // hidden
#define DD 300    // embed dim
#define DP 320    // embed dim padded to K%32==0

typedef __attribute__((ext_vector_type(8))) short short8;      // 8 x bf16
typedef __attribute__((ext_vector_type(4))) float f32x4;
typedef __attribute__((ext_vector_type(4))) unsigned int u32x4;

__device__ __forceinline__ unsigned short f2bf(float f) {
  unsigned u = __builtin_bit_cast(unsigned, f);
  u += 0x7fffu + ((u >> 16) & 1u);       // RNE
  return (unsigned short)(u >> 16);
}
__device__ __forceinline__ float sigm(float x) { return 1.f / (1.f + __expf(-x)); }
__device__ __forceinline__ float tanh_f(float x) {
  float t = __expf(-2.f * fabsf(x));
  float r = (1.f - t) / (1.f + t);
  return x < 0.f ? -r : r;
}

// 16B loads. sc1 = agent scope (MALL-coherent). NOT valid until s_waitcnt vmcnt(0).
__device__ __forceinline__ short8 load_frag(const unsigned short* p) {
  short8 r;
  asm volatile("global_load_dwordx4 %0, %1, off" : "=v"(r) : "v"(p));
  return r;
}
__device__ __forceinline__ u32x4 load_u4_sc1(const unsigned int* p) {
  u32x4 r;
  asm volatile("global_load_dwordx4 %0, %1, off sc1" : "=v"(r) : "v"(p));
  return r;
}
__device__ __forceinline__ unsigned ld_seq(const unsigned int* p) {
  return __hip_atomic_load(p, __ATOMIC_RELAXED, __HIP_MEMORY_SCOPE_AGENT);
}
__device__ __forceinline__ void st_u32(unsigned int* p, unsigned v) {
  __hip_atomic_store(p, v, __ATOMIC_RELAXED, __HIP_MEMORY_SCOPE_AGENT);
}

// ---------------- workspace layout (bytes) ----------------
// h panels are u32 elements: (tag16 << 16) | bf16. Element (b, c) of a
// [64 x 512] panel at u32 index: (c>>5)*2048 + (b>>4)*512 + ((c>>3)&3)*128
// + (b&15)*8 + (c&7). MFMA A-frag (m, kblk) = kblk*2048 + m*512 + lane*8.
// Tag convention: data produced at step s carries tag s+1; zeroed buffer = tag 0
// = "step -1 data" (zeros), which is the correct h(-1).
#define OFF_SEQ   0u          // l1seq[64], 64B spaced -> 4096; reserved to 8192
#define OFF_H1    8192u       // h1 ring [4][32768 u32] -> 524288
#define OFF_H2    532480u     // h2 ring [2][32768 u32] -> 262144
#define OFF_C2    794624u     // c2 [64][512] f32 -> 131072
#define OFF_XE    925696u     // xe bf16 frag layout [512][20480 u16] -> 20971520
#define OFF_W0    21897216u   // Wp0 [2048][832] bf16 -> 3407872
#define OFF_W1    25305088u   // Wp1 [2048][1024] bf16 -> 4194304
#define OFF_B0    29499392u   // bias0p [2048] f32
#define OFF_B1    29507584u   // bias1p [2048] f32
#define MEMSET_BYTES 794624u  // l1seq + h1 ring + h2 ring

// ---------------- weight prep (row-major Wp) ----------------
// grow = lblk*32 + l, gate = l>>3 (i,f,g,o), orig = gate*512 + lblk*8 + (l&7).
// Wp0 row: [ W_hh0 | W_ih0 | pad ] (A = [h1_prev | x_t]); Wp1 row: [ W_ih1 | W_hh1 ].
__global__ void prep_weights(const float* __restrict__ Wih0, const float* __restrict__ Whh0,
                             const float* __restrict__ bih0, const float* __restrict__ bhh0,
                             const float* __restrict__ Wih1, const float* __restrict__ Whh1,
                             const float* __restrict__ bih1, const float* __restrict__ bhh1,
                             unsigned short* __restrict__ Wp0, unsigned short* __restrict__ Wp1,
                             float* __restrict__ b0p, float* __restrict__ b1p)
{
  int idx = blockIdx.x * 256 + threadIdx.x;   // over 2048*1024
  int grow = idx >> 10;
  int k1 = idx & 1023;
  int l = grow & 31;
  int lb = grow >> 5;
  int gate = l >> 3;
  int orig = gate * 512 + lb * 8 + (l & 7);
  float v1 = (k1 < 512) ? Wih1[orig * 512 + k1] : Whh1[orig * 512 + (k1 - 512)];
  Wp1[idx] = f2bf(v1);
  if (k1 < 832) {
    float v0;
    if (k1 < 512)      v0 = Whh0[orig * 512 + k1];
    else if (k1 < 812) v0 = Wih0[orig * 300 + (k1 - 512)];
    else               v0 = 0.f;
    Wp0[grow * 832 + k1] = f2bf(v0);
  }
  if (k1 == 0) {
    b0p[grow] = bih0[orig] + bhh0[orig];
    b1p[grow] = bih1[orig] + bhh1[orig];
  }
}

// ---------------- embedding gather -> bf16 frag layout (no tags) ----------------
__global__ void gather_xe(const int* __restrict__ x, const float* __restrict__ emb,
                          unsigned short* __restrict__ xe)
{
  int idx = blockIdx.x * 256 + threadIdx.x;   // SS*BB*DP = 10485760
  int dk = idx % DP;
  int rem = idx / DP;
  int b = rem % BB;
  int t = rem / BB;
  int tok = x[b * SS + t];
  float v = (dk < DD) ? emb[(size_t)tok * DD + dk] : 0.f;
  size_t ua = (size_t)t * 20480 + (size_t)(dk >> 5) * 2048 + (size_t)(b >> 4) * 512
            + (size_t)((dk >> 3) & 3) * 128 + (size_t)(b & 15) * 8 + (dk & 7);
  xe[ua] = f2bf(v);
}

// ---------------- tagged-fragment poll: load until all tags match ----------------
// One vmcnt(0) per retry covers ALL G fragments (single RTT), plus any earlier
// issued (xe) loads. Extracts bf16 low halves into aout[0..G).
template<int G>
__device__ __forceinline__ void poll_frags(const unsigned int* __restrict__ slot,
                                           int kg0, int m, int lane, unsigned tagw,
                                           short8* aout)
{
  const unsigned int* base = slot + (size_t)kg0 * 2048 + (size_t)m * 512 + (size_t)lane * 8;
  u32x4 lo[G], hi[G];
  int guard = 0;
  for (;;) {
    #pragma unroll
    for (int j = 0; j < G; ++j) {
      lo[j] = load_u4_sc1(base + (size_t)j * 2048);
      hi[j] = load_u4_sc1(base + (size_t)j * 2048 + 4);
    }
    asm volatile("s_waitcnt vmcnt(0)" ::: "memory");
    __builtin_amdgcn_sched_barrier(0);
    unsigned orv = 0;
    #pragma unroll
    for (int j = 0; j < G; ++j) {
      orv |= (lo[j].x ^ tagw) | (lo[j].y ^ tagw) | (lo[j].z ^ tagw) | (lo[j].w ^ tagw)
           | (hi[j].x ^ tagw) | (hi[j].y ^ tagw) | (hi[j].z ^ tagw) | (hi[j].w ^ tagw);
    }
    if (__all((orv >> 16) == 0u)) break;            // all 8G tags fresh
    if (++guard > (1 << 15)) break;                 // liveness insurance
    __builtin_amdgcn_s_sleep(1);
  }
  #pragma unroll
  for (int j = 0; j < G; ++j) {
    union { short8 s; unsigned u[4]; } o;
    o.u[0] = (lo[j].x & 0xFFFFu) | (lo[j].y << 16);
    o.u[1] = (lo[j].z & 0xFFFFu) | (lo[j].w << 16);
    o.u[2] = (hi[j].x & 0xFFFFu) | (hi[j].y << 16);
    o.u[3] = (hi[j].z & 0xFFFFu) | (hi[j].w << 16);
    aout[j] = o.s;
  }
}

// ---------------- layer-0 persistent scan (64 blocks) ----------------
// Step t: reads h1(t-1) [slot (t+3)&3, tag t] + xe(t); writes h1(t) [slot t&3, tag t+1].
// Peer sync: implied by the data poll. L1 back-pressure: l1seq >= t-3 (ring-4).
__device__ __forceinline__ void scan_l0(
    int lblk,
    const unsigned short* __restrict__ xe,
    const unsigned short* __restrict__ Wp,
    const float* __restrict__ biasP,
    unsigned int* __restrict__ h1p,
    const unsigned int* __restrict__ l1seq,
    float (&gl)[2][2][64][36], float (&bias_sm)[32])
{
  constexpr int K = 832;
  const int tid  = threadIdx.x;
  const int lane = tid & 63;
  const int wave = tid >> 6;
  const int lrow = lane & 15;
  const int m    = wave & 3;
  const int q    = wave >> 2;
  const int qkb  = q * 13;

  if (tid < 32) bias_sm[tid] = biasP[lblk * 32 + tid];

  const unsigned short* wr0 = Wp + (size_t)(lblk * 32 + lrow) * K + qkb * 32 + (lane >> 4) * 8;
  const unsigned short* wr1 = wr0 + (size_t)16 * K;

  float creg = 0.f;
  const int pb = tid >> 3;
  const int ph = tid & 7;
  const size_t hstu = (size_t)(lblk >> 2) * 2048 + (size_t)(pb >> 4) * 512
                    + (size_t)(lblk & 3) * 128 + (size_t)(pb & 15) * 8 + ph;

  for (int t = 0; t < 512; ++t) {
    short8 a[13];
    if (q == 1) {   // xe fragments kg 16..25 -> a[3..12]; fly during the poll
      const unsigned short* xet = xe + (size_t)t * 20480;
      #pragma unroll
      for (int j = 3; j < 13; ++j)
        a[j] = load_frag(xet + (size_t)(qkb + j - 16) * 2048 + (size_t)m * 512 + lane * 8);
    }
    {
      const unsigned int* slotR = h1p + (size_t)((t + 3) & 3) * 32768;
      const unsigned tagw = (unsigned)t << 16;
      if (q == 0) poll_frags<13>(slotR, 0,  m, lane, tagw, a);
      else        poll_frags<3 >(slotR, 13, m, lane, tagw, a);
    }
    f32x4 acc0 = {0.f, 0.f, 0.f, 0.f};
    f32x4 acc1 = {0.f, 0.f, 0.f, 0.f};
    #pragma unroll
    for (int j = 0; j < 13; ++j) {
      short8 b0 = *(const short8*)(wr0 + j * 32);
      short8 b1 = *(const short8*)(wr1 + j * 32);
      acc0 = __builtin_amdgcn_mfma_f32_16x16x32_bf16(a[j], b0, acc0, 0, 0, 0);
      acc1 = __builtin_amdgcn_mfma_f32_16x16x32_bf16(a[j], b1, acc1, 0, 0, 0);
    }
    #pragma unroll
    for (int r = 0; r < 4; ++r) {
      const int bb = m * 16 + (lane >> 4) * 4 + r;
      gl[t & 1][q][bb][lrow]      = acc0[r];
      gl[t & 1][q][bb][16 + lrow] = acc1[r];
    }
    if (wave == 0) {   // ring-4 back-pressure from L1 (slack 3; usually instant)
      int guard = 0;
      for (;;) {
        unsigned v = ld_seq(l1seq + lane * 16);
        if (__all((int)v >= t - 3)) break;
        if (++guard > (1 << 15)) break;
        __builtin_amdgcn_s_sleep(4);
      }
    }
    __syncthreads();   // gl[t&1] complete + back-pressure cleared
    {
      const float* g0 = gl[t & 1][0][pb];
      const float* g1 = gl[t & 1][1][pb];
      float gi = g0[ph]      + g1[ph]      + bias_sm[ph];
      float gf = g0[8 + ph]  + g1[8 + ph]  + bias_sm[8 + ph];
      float gg = g0[16 + ph] + g1[16 + ph] + bias_sm[16 + ph];
      float go = g0[24 + ph] + g1[24 + ph] + bias_sm[24 + ph];
      float iv = sigm(gi), fv = sigm(gf), ov = sigm(go), gv = tanh_f(gg);
      creg = fv * creg + iv * gv;
      float hv = ov * tanh_f(creg);
      unsigned val = ((unsigned)(t + 1) << 16) | f2bf(hv);
      st_u32(h1p + (size_t)(t & 3) * 32768 + hstu, val);
    }
    // no trailing barrier: next iter stages gl[(t+1)&1]; stale readers see old tags
  }
}

// ---------------- layer-1 persistent scan (64 blocks) ----------------
// Step t: q=0 waves poll h1(t) [slot t&3, tag t+1]; q=1 waves poll h2(t-1)
// [slot (t+1)&1, tag t]. Writes h2(t) [slot t&1, tag t+1]; l1seq = t+1 after loads.
__device__ __forceinline__ void scan_l1(
    int lblk,
    const unsigned short* __restrict__ Wp,
    const float* __restrict__ biasP,
    const unsigned int* __restrict__ h1p,
    unsigned int* __restrict__ h2p,
    float* __restrict__ c2,
    unsigned int* __restrict__ l1seq,
    float (&gl)[2][2][64][36], float (&bias_sm)[32])
{
  constexpr int K = 1024;
  const int tid  = threadIdx.x;
  const int lane = tid & 63;
  const int wave = tid >> 6;
  const int lrow = lane & 15;
  const int m    = wave & 3;
  const int q    = wave >> 2;
  const int qkb  = q * 16;

  if (tid < 32) bias_sm[tid] = biasP[lblk * 32 + tid];

  const unsigned short* wr0 = Wp + (size_t)(lblk * 32 + lrow) * K + qkb * 32 + (lane >> 4) * 8;
  const unsigned short* wr1 = wr0 + (size_t)16 * K;

  float creg = 0.f;
  const int pb = tid >> 3;
  const int ph = tid & 7;
  const size_t hstu = (size_t)(lblk >> 2) * 2048 + (size_t)(pb >> 4) * 512
                    + (size_t)(lblk & 3) * 128 + (size_t)(pb & 15) * 8 + ph;

  for (int t = 0; t < 512; ++t) {
    short8 a[16];
    if (q == 0) {
      const unsigned int* slotR = h1p + (size_t)(t & 3) * 32768;
      poll_frags<16>(slotR, 0, m, lane, (unsigned)(t + 1) << 16, a);
    } else {
      const unsigned int* slotR = h2p + (size_t)((t + 1) & 1) * 32768;
      poll_frags<16>(slotR, 0, m, lane, (unsigned)t << 16, a);
    }
    f32x4 acc0 = {0.f, 0.f, 0.f, 0.f};
    f32x4 acc1 = {0.f, 0.f, 0.f, 0.f};
    #pragma unroll
    for (int j = 0; j < 16; ++j) {
      short8 b0 = *(const short8*)(wr0 + j * 32);
      short8 b1 = *(const short8*)(wr1 + j * 32);
      acc0 = __builtin_amdgcn_mfma_f32_16x16x32_bf16(a[j], b0, acc0, 0, 0, 0);
      acc1 = __builtin_amdgcn_mfma_f32_16x16x32_bf16(a[j], b1, acc1, 0, 0, 0);
    }
    #pragma unroll
    for (int r = 0; r < 4; ++r) {
      const int bb = m * 16 + (lane >> 4) * 4 + r;
      gl[t & 1][q][bb][lrow]      = acc0[r];
      gl[t & 1][q][bb][16 + lrow] = acc1[r];
    }
    __syncthreads();   // gl[t&1] complete; all waves' loads done
    if (tid == 0) st_u32(l1seq + lblk * 16, (unsigned)(t + 1));   // loads-complete report
    {
      const float* g0 = gl[t & 1][0][pb];
      const float* g1 = gl[t & 1][1][pb];
      float gi = g0[ph]      + g1[ph]      + bias_sm[ph];
      float gf = g0[8 + ph]  + g1[8 + ph]  + bias_sm[8 + ph];
      float gg = g0[16 + ph] + g1[16 + ph] + bias_sm[16 + ph];
      float go = g0[24 + ph] + g1[24 + ph] + bias_sm[24 + ph];
      float iv = sigm(gi), fv = sigm(gf), ov = sigm(go), gv = tanh_f(gg);
      creg = fv * creg + iv * gv;
      float hv = ov * tanh_f(creg);
      unsigned val = ((unsigned)(t + 1) << 16) | f2bf(hv);
      st_u32(h2p + (size_t)(t & 1) * 32768 + hstu, val);
      if (t == 511) c2[pb * HH + lblk * 8 + ph] = creg;
    }
  }
}

__attribute__((amdgpu_waves_per_eu(2, 2)))
__global__ void __launch_bounds__(512)
lstm_scan(const unsigned short* __restrict__ xe,
          const unsigned short* __restrict__ Wp0,
          const unsigned short* __restrict__ Wp1,
          const float* __restrict__ b0p, const float* __restrict__ b1p,
          unsigned int* __restrict__ h1p, unsigned int* __restrict__ h2p,
          float* __restrict__ c2, unsigned int* __restrict__ l1seq)
{
  __shared__ float gl[2][2][64][36];   // [parity][khalf][batch][gate]
  __shared__ float bias_sm[32];
  const int blk = blockIdx.x;
  if (blk < 64) scan_l0(blk,      xe, Wp0, b0p, h1p, l1seq, gl, bias_sm);
  else          scan_l1(blk - 64, Wp1, b1p, h1p, h2p, c2, l1seq, gl, bias_sm);
}

// ---------------- final projection: out = c2 @ Wout^T + bout ----------------
__global__ void outproj(const float* __restrict__ c2, const float* __restrict__ Wout,
                        const float* __restrict__ bout, float* __restrict__ out)
{
  int t = threadIdx.x;
  if (t >= 640) return;
  int b = t / 10, l = t % 10;
  float s = bout[l];
  #pragma unroll 8
  for (int h = 0; h < 512; ++h) s += c2[b * 512 + h] * Wout[l * 512 + h];
  out[b * 10 + l] = s;
}

extern "C" void kernel_launch(void* const* d_in, const int* in_sizes, int n_in,
                              void* d_out, int out_size, void* d_ws, size_t ws_size,
                              hipStream_t stream) {
  (void)in_sizes; (void)n_in; (void)out_size; (void)ws_size;
  const int*   x    = (const int*)  d_in[0];
  const float* emb  = (const float*)d_in[1];
  const float* Wih0 = (const float*)d_in[2];
  const float* Whh0 = (const float*)d_in[3];
  const float* bih0 = (const float*)d_in[4];
  const float* bhh0 = (const float*)d_in[5];
  const float* Wih1 = (const float*)d_in[6];
  const float* Whh1 = (const float*)d_in[7];
  const float* bih1 = (const float*)d_in[8];
  const float* bhh1 = (const float*)d_in[9];
  const float* Wout = (const float*)d_in[10];
  const float* bout = (const float*)d_in[11];
  float* out = (float*)d_out;

  char* ws = (char*)d_ws;
  unsigned int*   l1s = (unsigned int*)  (ws + OFF_SEQ);
  unsigned int*   h1p = (unsigned int*)  (ws + OFF_H1);
  unsigned int*   h2p = (unsigned int*)  (ws + OFF_H2);
  float*          c2  = (float*)         (ws + OFF_C2);
  unsigned short* xe  = (unsigned short*)(ws + OFF_XE);
  unsigned short* Wp0 = (unsigned short*)(ws + OFF_W0);
  unsigned short* Wp1 = (unsigned short*)(ws + OFF_W1);
  float*          b0p = (float*)         (ws + OFF_B0);
  float*          b1p = (float*)         (ws + OFF_B1);

  hipMemsetAsync(ws, 0, MEMSET_BYTES, stream);   // l1seq + h rings = 0 (tag 0)
  prep_weights<<<8192, 256, 0, stream>>>(Wih0, Whh0, bih0, bhh0, Wih1, Whh1, bih1, bhh1,
                                         Wp0, Wp1, b0p, b1p);
  gather_xe<<<40960, 256, 0, stream>>>(x, emb, xe);
  lstm_scan<<<128, 512, 0, stream>>>(xe, Wp0, Wp1, b0p, b1p, h1p, h2p, c2, l1s);
  outproj<<<1, 640, 0, stream>>>(c2, Wout, bout, out);
}

// Round 11
// 4799.541 us; speedup vs baseline: 1.1984x; 1.1984x over previous
//
#include <hip/hip_runtime.h>
#include <hip/hip_bf16.h>
#include <stdint.h>

// Problem dims
#define BB 64     // batch
#define SS 512    // seq len
#define HH 512    // hidden
#define DD 300    // embed dim
#define DP 320    // embed dim padded to K%32==0

#define POISON 0x7F7F7F7Fu   // two bf16 0x7F7F = 3.39e38; impossible for |h|<1

typedef __attribute__((ext_vector_type(8))) short short8;      // 8 x bf16
typedef __attribute__((ext_vector_type(4))) float f32x4;
typedef __attribute__((ext_vector_type(4))) unsigned int u32x4;

__device__ __forceinline__ unsigned short f2bf(float f) {
  unsigned u = __builtin_bit_cast(unsigned, f);
  u += 0x7fffu + ((u >> 16) & 1u);       // RNE
  return (unsigned short)(u >> 16);
}
__device__ __forceinline__ float sigm(float x) { return 1.f / (1.f + __expf(-x)); }
__device__ __forceinline__ float tanh_f(float x) {
  float t = __expf(-2.f * fabsf(x));
  float r = (1.f - t) / (1.f + t);
  return x < 0.f ? -r : r;
}

// 16B loads. sc1 = agent scope (MALL-coherent). NOT valid until s_waitcnt vmcnt(0).
__device__ __forceinline__ short8 load_frag(const unsigned short* p) {
  short8 r;
  asm volatile("global_load_dwordx4 %0, %1, off" : "=v"(r) : "v"(p));
  return r;
}
__device__ __forceinline__ short8 load_frag_sc1(const unsigned short* p) {
  short8 r;
  asm volatile("global_load_dwordx4 %0, %1, off sc1" : "=v"(r) : "v"(p));
  return r;
}
__device__ __forceinline__ unsigned ld_seq(const unsigned int* p) {
  return __hip_atomic_load(p, __ATOMIC_RELAXED, __HIP_MEMORY_SCOPE_AGENT);
}
__device__ __forceinline__ void st_u32(unsigned int* p, unsigned v) {
  __hip_atomic_store(p, v, __ATOMIC_RELAXED, __HIP_MEMORY_SCOPE_AGENT);
}
__device__ __forceinline__ void store_poison4(unsigned int* p) {
  u32x4 v = {POISON, POISON, POISON, POISON};
  asm volatile("global_store_dwordx4 %0, %1, off sc1" :: "v"(p), "v"(v) : "memory");
}
__device__ __forceinline__ bool frag_stale(short8 v) {
  union { short8 s; unsigned u[4]; } c; c.s = v;
  return (c.u[0] == POISON) | (c.u[1] == POISON) | (c.u[2] == POISON) | (c.u[3] == POISON);
}

// Canary-throttled fragment poll: poll frag0 (1KB/wave) until non-poison, then
// bulk-load the rest once + selective straggler retry. p0 is lane-resolved.
template<int NH>
__device__ __forceinline__ void poll_h(const unsigned short* p0, short8* a) {
  int guard = 0;
  for (;;) {
    a[0] = load_frag_sc1(p0);
    asm volatile("s_waitcnt vmcnt(0)" ::: "memory");
    __builtin_amdgcn_sched_barrier(0);
    if (!__any(frag_stale(a[0]))) break;
    if (++guard > (1 << 16)) break;      // liveness insurance
    __builtin_amdgcn_s_sleep(1);
  }
  if (NH > 1) {
    #pragma unroll
    for (int j = 1; j < NH; ++j) a[j] = load_frag_sc1(p0 + (size_t)j * 2048);
    asm volatile("s_waitcnt vmcnt(0)" ::: "memory");
    __builtin_amdgcn_sched_barrier(0);
    guard = 0;
    for (;;) {
      unsigned mm = 0;
      #pragma unroll
      for (int j = 1; j < NH; ++j)
        if (__any(frag_stale(a[j]))) mm |= 1u << j;
      if (!mm) break;
      if (++guard > (1 << 16)) break;
      __builtin_amdgcn_s_sleep(1);
      #pragma unroll
      for (int j = 1; j < NH; ++j)
        if ((mm >> j) & 1u) a[j] = load_frag_sc1(p0 + (size_t)j * 2048);
      asm volatile("s_waitcnt vmcnt(0)" ::: "memory");
      __builtin_amdgcn_sched_barrier(0);
    }
  }
}

// ---------------- workspace layout (bytes) ----------------
// bf16 frag-ready h panels (64KB each): element (b,c) at u16 addr
// (c>>5)*2048 + (b>>4)*512 + ((c>>3)&3)*128 + (b&15)*8 + (c&7); A-frag
// (m,kblk) = kblk*2048 + m*512 + lane*8. Rings depth 4. Slot protocol:
// h(t) lives in slot t&3; owner poisons slot (t+2)&3 at end of step t.
// Consumers poll for non-poison (canary+bulk). h(-1) = zeros in slot 3.
#define OFF_SEQ   0u          // l1seq[64], 64B spaced -> 4096; reserved 8192
#define OFF_H1    8192u       // h1 ring [4][32768 u16] -> 262144
#define OFF_H2    270336u     // h2 ring [4][32768 u16] -> 262144
#define OFF_C2    532480u     // c2 [64][512] f32 -> 131072
#define OFF_XE    663552u     // xe bf16 frag layout [512][20480 u16] -> 20971520
#define OFF_W0    21635072u   // Wp0 [2048][832] bf16 -> 3407872
#define OFF_W1    25042944u   // Wp1 [2048][1024] bf16 -> 4194304
#define OFF_B0    29237248u   // bias0p [2048] f32
#define OFF_B1    29245440u   // bias1p [2048] f32

// ---------------- weight prep (row-major Wp) ----------------
// grow = lblk*32 + l, gate = l>>3 (i,f,g,o), orig = gate*512 + lblk*8 + (l&7).
// Wp0 row: [ W_hh0 | W_ih0 | pad ] (A = [h1_prev | x_t]); Wp1 row: [ W_ih1 | W_hh1 ].
__global__ void prep_weights(const float* __restrict__ Wih0, const float* __restrict__ Whh0,
                             const float* __restrict__ bih0, const float* __restrict__ bhh0,
                             const float* __restrict__ Wih1, const float* __restrict__ Whh1,
                             const float* __restrict__ bih1, const float* __restrict__ bhh1,
                             unsigned short* __restrict__ Wp0, unsigned short* __restrict__ Wp1,
                             float* __restrict__ b0p, float* __restrict__ b1p)
{
  int idx = blockIdx.x * 256 + threadIdx.x;   // over 2048*1024
  int grow = idx >> 10;
  int k1 = idx & 1023;
  int l = grow & 31;
  int lb = grow >> 5;
  int gate = l >> 3;
  int orig = gate * 512 + lb * 8 + (l & 7);
  float v1 = (k1 < 512) ? Wih1[orig * 512 + k1] : Whh1[orig * 512 + (k1 - 512)];
  Wp1[idx] = f2bf(v1);
  if (k1 < 832) {
    float v0;
    if (k1 < 512)      v0 = Whh0[orig * 512 + k1];
    else if (k1 < 812) v0 = Wih0[orig * 300 + (k1 - 512)];
    else               v0 = 0.f;
    Wp0[grow * 832 + k1] = f2bf(v0);
  }
  if (k1 == 0) {
    b0p[grow] = bih0[orig] + bhh0[orig];
    b1p[grow] = bih1[orig] + bhh1[orig];
  }
}

// ---------------- embedding gather -> bf16 frag layout ----------------
__global__ void gather_xe(const int* __restrict__ x, const float* __restrict__ emb,
                          unsigned short* __restrict__ xe)
{
  int idx = blockIdx.x * 256 + threadIdx.x;   // SS*BB*DP = 10485760
  int dk = idx % DP;
  int rem = idx / DP;
  int b = rem % BB;
  int t = rem / BB;
  int tok = x[b * SS + t];
  float v = (dk < DD) ? emb[(size_t)tok * DD + dk] : 0.f;
  size_t ua = (size_t)t * 20480 + (size_t)(dk >> 5) * 2048 + (size_t)(b >> 4) * 512
            + (size_t)((dk >> 3) & 3) * 128 + (size_t)(b & 15) * 8 + (dk & 7);
  xe[ua] = f2bf(v);
}

// ---------------- layer-0 persistent scan (64 blocks) ----------------
// Step t: polls h1(t-1) [slot (t+3)&3, non-poison], writes h1(t) [slot t&3].
// End of step (wave0): wait l1seq >= t-1, then poison slot (t+2)&3 (own cells).
// Poison/data ordering: wave0's next-step canary vmcnt(0) drains the poison
// before any later h is produced -> consumers can never poll pre-poison slots.
__device__ __forceinline__ void scan_l0(
    int lblk,
    const unsigned short* __restrict__ xe,
    const unsigned short* __restrict__ Wp,
    const float* __restrict__ biasP,
    unsigned short* __restrict__ h1r,
    unsigned int* __restrict__ l1seq,
    float (&gl)[2][2][64][36], float (&bias_sm)[32])
{
  constexpr int K = 832;
  const int tid  = threadIdx.x;
  const int lane = tid & 63;
  const int wave = tid >> 6;
  const int lrow = lane & 15;
  const int m    = wave & 3;
  const int q    = wave >> 2;
  const int qkb  = q * 13;

  if (tid < 32) bias_sm[tid] = biasP[lblk * 32 + tid];

  const unsigned short* wr0 = Wp + (size_t)(lblk * 32 + lrow) * K + qkb * 32 + (lane >> 4) * 8;
  const unsigned short* wr1 = wr0 + (size_t)16 * K;

  float creg = 0.f;
  const int pb = tid >> 3;
  const int ph = tid & 7;
  const size_t hstu = (size_t)(lblk >> 2) * 2048 + (size_t)(pb >> 4) * 512
                    + (size_t)(lblk & 3) * 128 + (size_t)(pb & 15) * 8 + ph;
  const size_t pzi  = (size_t)(lblk >> 2) * 1024 + (size_t)(lane >> 4) * 256
                    + (size_t)(lblk & 3) * 64 + (size_t)(lane & 15) * 4;

  for (int t = 0; t < 512; ++t) {
    short8 a[13];
    const unsigned short* hA = h1r + (size_t)((t + 3) & 3) * 32768;
    const unsigned short* p0 = hA + (size_t)qkb * 2048 + (size_t)m * 512 + lane * 8;
    if (q == 1) {
      const unsigned short* xet = xe + (size_t)t * 20480;
      #pragma unroll
      for (int j = 3; j < 13; ++j)
        a[j] = load_frag(xet + (size_t)(qkb + j - 16) * 2048 + (size_t)m * 512 + lane * 8);
      poll_h<3>(p0, a);     // h1 frags kg 13..15
    } else {
      poll_h<13>(p0, a);    // h1 frags kg 0..12
    }
    // ---- MFMA ----
    f32x4 acc0 = {0.f, 0.f, 0.f, 0.f};
    f32x4 acc1 = {0.f, 0.f, 0.f, 0.f};
    #pragma unroll
    for (int j = 0; j < 13; ++j) {
      short8 b0 = *(const short8*)(wr0 + j * 32);
      short8 b1 = *(const short8*)(wr1 + j * 32);
      acc0 = __builtin_amdgcn_mfma_f32_16x16x32_bf16(a[j], b0, acc0, 0, 0, 0);
      acc1 = __builtin_amdgcn_mfma_f32_16x16x32_bf16(a[j], b1, acc1, 0, 0, 0);
    }
    #pragma unroll
    for (int r = 0; r < 4; ++r) {
      const int bb = m * 16 + (lane >> 4) * 4 + r;
      gl[t & 1][q][bb][lrow]      = acc0[r];
      gl[t & 1][q][bb][16 + lrow] = acc1[r];
    }
    __syncthreads();    // the ONE barrier per step (parity dbuf makes it safe)
    {
      const float* g0 = gl[t & 1][0][pb];
      const float* g1 = gl[t & 1][1][pb];
      float gi = g0[ph]      + g1[ph]      + bias_sm[ph];
      float gf = g0[8 + ph]  + g1[8 + ph]  + bias_sm[8 + ph];
      float gg = g0[16 + ph] + g1[16 + ph] + bias_sm[16 + ph];
      float go = g0[24 + ph] + g1[24 + ph] + bias_sm[24 + ph];
      float iv = sigm(gi), fv = sigm(gf), ov = sigm(go), gv = tanh_f(gg);
      creg = fv * creg + iv * gv;
      float hv = ov * tanh_f(creg);
      unsigned short hb = f2bf(hv);
      unsigned pair = (unsigned)hb | ((unsigned)(unsigned short)__shfl_down((int)hb, 1) << 16);
      if ((ph & 1) == 0)
        st_u32((unsigned*)(h1r + (size_t)(t & 3) * 32768 + hstu), pair);
    }
    // ---- tail (wave0 only, overlaps peers' production): L1 gate + poison ----
    if (wave == 0 && t < 511) {
      int guard = 0;
      for (;;) {
        int v = (int)ld_seq(l1seq + lane * 16);
        if (__all(v >= t - 1)) break;
        if (++guard > (1 << 16)) break;
        __builtin_amdgcn_s_sleep(2);
      }
      store_poison4((unsigned*)(h1r + (size_t)((t + 2) & 3) * 32768) + pzi);
    }
  }
}

// ---------------- layer-1 persistent scan (64 blocks) ----------------
// Step t: q=0 polls h1(t) [slot t&3]; q=1 polls h2(t-1) [slot (t+3)&3] --
// concurrently, each on its own operand. Writes h2(t) [slot t&3]; stores
// l1seq=t+1 after the barrier (loads provably done); wave0 poisons h2 slot
// (t+2)&3 (peer-read-safety automatic via the h2 recurrence).
__device__ __forceinline__ void scan_l1(
    int lblk,
    const unsigned short* __restrict__ Wp,
    const float* __restrict__ biasP,
    const unsigned short* __restrict__ h1r,
    unsigned short* __restrict__ h2r,
    float* __restrict__ c2,
    unsigned int* __restrict__ l1seq,
    float (&gl)[2][2][64][36], float (&bias_sm)[32])
{
  constexpr int K = 1024;
  const int tid  = threadIdx.x;
  const int lane = tid & 63;
  const int wave = tid >> 6;
  const int lrow = lane & 15;
  const int m    = wave & 3;
  const int q    = wave >> 2;
  const int qkb  = q * 16;

  if (tid < 32) bias_sm[tid] = biasP[lblk * 32 + tid];

  const unsigned short* wr0 = Wp + (size_t)(lblk * 32 + lrow) * K + qkb * 32 + (lane >> 4) * 8;
  const unsigned short* wr1 = wr0 + (size_t)16 * K;

  float creg = 0.f;
  const int pb = tid >> 3;
  const int ph = tid & 7;
  const size_t hstu = (size_t)(lblk >> 2) * 2048 + (size_t)(pb >> 4) * 512
                    + (size_t)(lblk & 3) * 128 + (size_t)(pb & 15) * 8 + ph;
  const size_t pzi  = (size_t)(lblk >> 2) * 1024 + (size_t)(lane >> 4) * 256
                    + (size_t)(lblk & 3) * 64 + (size_t)(lane & 15) * 4;

  for (int t = 0; t < 512; ++t) {
    short8 a[16];
    const unsigned short* base = (q == 0)
        ? (h1r + (size_t)(t & 3) * 32768)          // h1(t)
        : (h2r + (size_t)((t + 3) & 3) * 32768);   // h2(t-1)
    poll_h<16>(base + (size_t)m * 512 + lane * 8, a);
    // ---- MFMA ----
    f32x4 acc0 = {0.f, 0.f, 0.f, 0.f};
    f32x4 acc1 = {0.f, 0.f, 0.f, 0.f};
    #pragma unroll
    for (int j = 0; j < 16; ++j) {
      short8 b0 = *(const short8*)(wr0 + j * 32);
      short8 b1 = *(const short8*)(wr1 + j * 32);
      acc0 = __builtin_amdgcn_mfma_f32_16x16x32_bf16(a[j], b0, acc0, 0, 0, 0);
      acc1 = __builtin_amdgcn_mfma_f32_16x16x32_bf16(a[j], b1, acc1, 0, 0, 0);
    }
    #pragma unroll
    for (int r = 0; r < 4; ++r) {
      const int bb = m * 16 + (lane >> 4) * 4 + r;
      gl[t & 1][q][bb][lrow]      = acc0[r];
      gl[t & 1][q][bb][16 + lrow] = acc1[r];
    }
    __syncthreads();
    if (tid == 0) st_u32(l1seq + lblk * 16, (unsigned)(t + 1));  // loads done
    {
      const float* g0 = gl[t & 1][0][pb];
      const float* g1 = gl[t & 1][1][pb];
      float gi = g0[ph]      + g1[ph]      + bias_sm[ph];
      float gf = g0[8 + ph]  + g1[8 + ph]  + bias_sm[8 + ph];
      float gg = g0[16 + ph] + g1[16 + ph] + bias_sm[16 + ph];
      float go = g0[24 + ph] + g1[24 + ph] + bias_sm[24 + ph];
      float iv = sigm(gi), fv = sigm(gf), ov = sigm(go), gv = tanh_f(gg);
      creg = fv * creg + iv * gv;
      float hv = ov * tanh_f(creg);
      unsigned short hb = f2bf(hv);
      unsigned pair = (unsigned)hb | ((unsigned)(unsigned short)__shfl_down((int)hb, 1) << 16);
      if ((ph & 1) == 0)
        st_u32((unsigned*)(h2r + (size_t)(t & 3) * 32768 + hstu), pair);
      if (t == 511) c2[pb * HH + lblk * 8 + ph] = creg;
    }
    if (wave == 0 && t < 511)
      store_poison4((unsigned*)(h2r + (size_t)((t + 2) & 3) * 32768) + pzi);
  }
}

__attribute__((amdgpu_waves_per_eu(2, 2)))
__global__ void __launch_bounds__(512)
lstm_scan(const unsigned short* __restrict__ xe,
          const unsigned short* __restrict__ Wp0,
          const unsigned short* __restrict__ Wp1,
          const float* __restrict__ b0p, const float* __restrict__ b1p,
          unsigned short* __restrict__ h1r, unsigned short* __restrict__ h2r,
          float* __restrict__ c2, unsigned int* __restrict__ l1seq)
{
  __shared__ float gl[2][2][64][36];   // [step parity][khalf][batch][gate col]
  __shared__ float bias_sm[32];
  const int blk = blockIdx.x;
  if (blk < 64) scan_l0(blk,      xe, Wp0, b0p, h1r, l1seq, gl, bias_sm);
  else          scan_l1(blk - 64, Wp1, b1p, h1r, h2r, c2, l1seq, gl, bias_sm);
}

// ---------------- final projection: out = c2 @ Wout^T + bout ----------------
__global__ void outproj(const float* __restrict__ c2, const float* __restrict__ Wout,
                        const float* __restrict__ bout, float* __restrict__ out)
{
  int t = threadIdx.x;
  if (t >= 640) return;
  int b = t / 10, l = t % 10;
  float s = bout[l];
  #pragma unroll 8
  for (int h = 0; h < 512; ++h) s += c2[b * 512 + h] * Wout[l * 512 + h];
  out[b * 10 + l] = s;
}

extern "C" void kernel_launch(void* const* d_in, const int* in_sizes, int n_in,
                              void* d_out, int out_size, void* d_ws, size_t ws_size,
                              hipStream_t stream) {
  (void)in_sizes; (void)n_in; (void)out_size; (void)ws_size;
  const int*   x    = (const int*)  d_in[0];
  const float* emb  = (const float*)d_in[1];
  const float* Wih0 = (const float*)d_in[2];
  const float* Whh0 = (const float*)d_in[3];
  const float* bih0 = (const float*)d_in[4];
  const float* bhh0 = (const float*)d_in[5];
  const float* Wih1 = (const float*)d_in[6];
  const float* Whh1 = (const float*)d_in[7];
  const float* bih1 = (const float*)d_in[8];
  const float* bhh1 = (const float*)d_in[9];
  const float* Wout = (const float*)d_in[10];
  const float* bout = (const float*)d_in[11];
  float* out = (float*)d_out;

  char* ws = (char*)d_ws;
  unsigned int*   l1s = (unsigned int*)  (ws + OFF_SEQ);
  unsigned short* h1r = (unsigned short*)(ws + OFF_H1);
  unsigned short* h2r = (unsigned short*)(ws + OFF_H2);
  float*          c2  = (float*)         (ws + OFF_C2);
  unsigned short* xe  = (unsigned short*)(ws + OFF_XE);
  unsigned short* Wp0 = (unsigned short*)(ws + OFF_W0);
  unsigned short* Wp1 = (unsigned short*)(ws + OFF_W1);
  float*          b0p = (float*)         (ws + OFF_B0);
  float*          b1p = (float*)         (ws + OFF_B1);

  // Ring init: slots 0-2 POISON (polled before first write); slot 3 = h(-1) = 0.
  hipMemsetAsync(ws + OFF_SEQ,           0x00, 8192,   stream);  // l1seq
  hipMemsetAsync(ws + OFF_H1,            0x7F, 196608, stream);  // h1 s0-2 poison
  hipMemsetAsync(ws + OFF_H1 + 196608u,  0x00, 65536,  stream);  // h1 s3 zeros
  hipMemsetAsync(ws + OFF_H2,            0x7F, 196608, stream);  // h2 s0-2 poison
  hipMemsetAsync(ws + OFF_H2 + 196608u,  0x00, 65536,  stream);  // h2 s3 zeros

  prep_weights<<<8192, 256, 0, stream>>>(Wih0, Whh0, bih0, bhh0, Wih1, Whh1, bih1, bhh1,
                                         Wp0, Wp1, b0p, b1p);
  gather_xe<<<40960, 256, 0, stream>>>(x, emb, xe);
  lstm_scan<<<128, 512, 0, stream>>>(xe, Wp0, Wp1, b0p, b1p, h1r, h2r, c2, l1s);
  outproj<<<1, 640, 0, stream>>>(c2, Wout, bout, out);
}